// Round 7
// baseline (660.452 us; speedup 1.0000x reference)
//
#include <hip/hip_runtime.h>
#include <hip/hip_bf16.h>

#define CIN_B 512
#define CIN_F0 40
#define CIN_D 32
#define CIN_S 200

typedef short bf16x8 __attribute__((ext_vector_type(8)));
typedef float floatx16 __attribute__((ext_vector_type(16)));

__device__ __forceinline__ float bits2f(unsigned int u) {
    union { unsigned int i; float f; } c; c.i = u; return c.f;
}
__device__ __forceinline__ unsigned short f2b(float f) {
    union { float f; unsigned int i; } c; c.f = f;
    unsigned int i = c.i;
    return (unsigned short)((i + 0x7fffu + ((i >> 16) & 1u)) >> 16);  // RNE
}
__device__ __forceinline__ float b2f(unsigned short u) {
    return bits2f(((unsigned int)u) << 16);
}

// scale 8 packed bf16 by fp32 s, RNE repack. hi uses raw bitcast (low-16
// contamination is <=2^-16 relative, absorbed by the bf16 round).
__device__ __forceinline__ bf16x8 scale8(bf16x8 v, float s) {
    union { bf16x8 h; unsigned int w[4]; float f[4]; } in, out;
    in.h = v;
#pragma unroll
    for (int q = 0; q < 4; ++q) {
        float lo = bits2f(in.w[q] << 16) * s;
        float hi = in.f[q] * s;
        __hip_bfloat162 p = __float22bfloat162_rn(make_float2(lo, hi));
        out.w[q] = *(unsigned int*)&p;   // x(lo) in low 16, y(hi) in high 16
    }
    return out.h;
}

// Wtk[kc][nn 0..255][kw 0..15] = bf16(W[(i*FI + kk*16+kw)*200 + nn]); kc = i*KCPI+kk.
template <int FI, int KCPI>
__global__ __launch_bounds__(256) void prep_w(const float* __restrict__ W,
                                              unsigned short* __restrict__ Wtk) {
    const int kc = blockIdx.x;
    const int nn = threadIdx.x;
    const int i = kc / KCPI;
    const int kk = kc - i * KCPI;
    unsigned short v[16];
#pragma unroll
    for (int kw = 0; kw < 16; ++kw) {
        int j = kk * 16 + kw;
        float f = 0.f;
        if (j < FI && nn < CIN_S) f = W[(size_t)(i * FI + j) * CIN_S + nn];
        v[kw] = f2b(f);
    }
    uint4* dst = (uint4*)(Wtk + ((size_t)kc * 256 + nn) * 16);
    dst[0] = ((const uint4*)v)[0];
    dst[1] = ((const uint4*)v)[1];
}

// fused variant for the two big weight matrices (same shape)
__global__ __launch_bounds__(256) void prep_w2(const float* __restrict__ Wa,
                                               unsigned short* __restrict__ Wta,
                                               const float* __restrict__ Wb,
                                               unsigned short* __restrict__ Wtb) {
    const int half = blockIdx.x >= 560;
    const int kc = half ? blockIdx.x - 560 : blockIdx.x;
    const float* W = half ? Wb : Wa;
    unsigned short* Wtk = half ? Wtb : Wta;
    const int nn = threadIdx.x;
    const int i = kc / 14;
    const int kk = kc - i * 14;
    unsigned short v[16];
#pragma unroll
    for (int kw = 0; kw < 16; ++kw) {
        int j = kk * 16 + kw;
        float f = 0.f;
        if (j < CIN_S && nn < CIN_S) f = W[(size_t)(i * CIN_S + j) * CIN_S + nn];
        v[kw] = f2b(f);
    }
    uint4* dst = (uint4*)(Wtk + ((size_t)kc * 256 + nn) * 16);
    dst[0] = ((const uint4*)v)[0];
    dst[1] = ((const uint4*)v)[1];
}

// X0h[b][d][i(pad 48)] = bf16(x0[b][i][d]);  Xs[b][i][d] = fp32 x0.
__global__ __launch_bounds__(256) void prep_x(const float* __restrict__ X,
                                              unsigned short* __restrict__ X0h,
                                              float* __restrict__ Xs) {
    int e = blockIdx.x * 256 + threadIdx.x;   // 512*40*32
    int d = e & 31;
    int rest = e >> 5;
    int i = rest % CIN_F0;
    int b = rest / CIN_F0;
    float v = X[e];
    Xs[e] = v;
    X0h[((size_t)b * CIN_D + d) * 48 + i] = f2b(v);
    if (e < CIN_B * CIN_D * 8) {     // zero pads i=40..47
        int q = e & 7, dd = (e >> 3) & 31, bb = e >> 8;
        X0h[((size_t)bb * CIN_D + dd) * 48 + 40 + q] = 0;
    }
}

// Layer: acc[n,d] = sum_i sum_j Wt[n,(i,j)] * bf16(h[j,d]*x0[i,d]); x0 folded
// into B in-register (scale8), acc is the MFMA accumulator directly.
// Grid: 256 blocks (2 b each) x 14 waves = 7 n-tiles x 2 j-halves; partials
// combined via LDS; epilogue writes bf16 H (layers 1,2) and fp32 d-sums to out.
// mfma_f32_32x32x16_bf16: A[m=lane&31][k=(lane>>5)*8+e] (m = n-row);
// B[k][col=lane&31] (col = d); C/D col=lane&31, row=(reg&3)+8*(reg>>2)+4*(lane>>5).
template <int KCPI, int JROW, bool WH>
__global__ __launch_bounds__(896, 4)
void cin_layer(const unsigned short* __restrict__ Hin,   // [b][32][JROW] bf16
               const float* __restrict__ Xs,             // [b][40][32] fp32
               const unsigned short* __restrict__ Wtk,   // [kc][256][16] bf16
               unsigned short* __restrict__ Hout,        // [b][32][224] bf16
               float* __restrict__ out, int loff) {      // [b][600] fp32
    constexpr int CH = (KCPI + 1) / 2;
    __shared__ float cb[7][2][16][64];   // 57,344 B
    const int b0 = blockIdx.x * 2;
    const int wave = threadIdx.x >> 6;
    const int lane = threadIdx.x & 63;
    const int tile = wave % 7;
    const int jh = wave / 7;             // 0 or 1
    const int l32 = lane & 31, hl = lane >> 5;
    const int kk0 = jh ? CH : 0;
    const int NK = jh ? (KCPI - CH) : CH;

    // B-frags: raw h, i-invariant, resident in VGPRs (56 regs for CH=7, 2 b)
    bf16x8 Bf0[CH], Bf1[CH];
    {
        const unsigned short* h0 = Hin + ((size_t)b0 * CIN_D + l32) * JROW + hl * 8;
        const unsigned short* h1 = h0 + (size_t)CIN_D * JROW;
#pragma unroll
        for (int kk = 0; kk < CH; ++kk) {
            if (kk < NK) {
                Bf0[kk] = *(const bf16x8*)(h0 + (kk0 + kk) * 16);
                Bf1[kk] = *(const bf16x8*)(h1 + (kk0 + kk) * 16);
            }
        }
    }

    const unsigned short* Abase =
        Wtk + ((size_t)(tile * 32 + l32) * 16 + hl * 8) + (size_t)kk0 * 4096;
    const float* xs0 = Xs + (size_t)b0 * (CIN_F0 * CIN_D) + l32;

    floatx16 acc0, acc1;
#pragma unroll
    for (int r = 0; r < 16; ++r) { acc0[r] = 0.f; acc1[r] = 0.f; }

#pragma unroll 1
    for (int i = 0; i < CIN_F0; ++i) {
        const float x0 = xs0[(size_t)i * CIN_D];
        const float x1 = xs0[(size_t)i * CIN_D + CIN_F0 * CIN_D];
        const unsigned short* Ai = Abase + (size_t)i * (KCPI * 4096);
#pragma unroll
        for (int kk = 0; kk < CH; ++kk) {
            if (kk < NK) {
                const bf16x8 Af = *(const bf16x8*)(Ai + kk * 4096);
                acc0 = __builtin_amdgcn_mfma_f32_32x32x16_bf16(
                    Af, scale8(Bf0[kk], x0), acc0, 0, 0, 0);
                acc1 = __builtin_amdgcn_mfma_f32_32x32x16_bf16(
                    Af, scale8(Bf1[kk], x1), acc1, 0, 0, 0);
            }
        }
    }

    // combine j-halves via LDS
    if (jh == 1) {
#pragma unroll
        for (int r = 0; r < 16; ++r) {
            cb[tile][0][r][lane] = acc0[r];
            cb[tile][1][r][lane] = acc1[r];
        }
    }
    __syncthreads();
    if (jh == 0) {
#pragma unroll
        for (int r = 0; r < 16; ++r) {
            acc0[r] += cb[tile][0][r][lane];
            acc1[r] += cb[tile][1][r][lane];
        }

        if constexpr (WH) {   // H store: C[n][d] -> Hout[b][d][n] bf16
#pragma unroll
            for (int bb = 0; bb < 2; ++bb) {
                const floatx16& a = bb ? acc1 : acc0;
                unsigned short* dst =
                    Hout + ((size_t)(b0 + bb) * CIN_D + l32) * 224 + tile * 32;
#pragma unroll
                for (int qd = 0; qd < 4; ++qd) {
                    ushort4 pk;
                    pk.x = f2b(a[4 * qd + 0]);
                    pk.y = f2b(a[4 * qd + 1]);
                    pk.z = f2b(a[4 * qd + 2]);
                    pk.w = f2b(a[4 * qd + 3]);
                    *(ushort4*)&dst[8 * qd + 4 * hl] = pk;
                }
            }
        }

        // fused d-reduction: sum over col=l32 within each hl half, write fp32
#pragma unroll
        for (int bb = 0; bb < 2; ++bb) {
            floatx16 a = bb ? acc1 : acc0;
#pragma unroll
            for (int r = 0; r < 16; ++r) {
                float v = a[r];
                v += __shfl_xor(v, 1);
                v += __shfl_xor(v, 2);
                v += __shfl_xor(v, 4);
                v += __shfl_xor(v, 8);
                v += __shfl_xor(v, 16);
                a[r] = v;
            }
            if (l32 == 0) {
#pragma unroll
                for (int r = 0; r < 16; ++r) {
                    int n = tile * 32 + (r & 3) + 8 * (r >> 2) + 4 * hl;
                    if (n < CIN_S)
                        out[(size_t)(b0 + bb) * (3 * CIN_S) + loff + n] = a[r];
                }
            }
        }
    }
}

extern "C" void kernel_launch(void* const* d_in, const int* in_sizes, int n_in,
                              void* d_out, int out_size, void* d_ws, size_t ws_size,
                              hipStream_t stream) {
    const float* X  = (const float*)d_in[0];
    const float* W0 = (const float*)d_in[1];
    const float* W1 = (const float*)d_in[2];
    const float* W2 = (const float*)d_in[3];
    float* out = (float*)d_out;

    unsigned short* Wtk1 = (unsigned short*)d_ws;            // 120*4096
    unsigned short* Wtk2 = Wtk1 + (size_t)120 * 4096;        // 560*4096
    unsigned short* Wtk3 = Wtk2 + (size_t)560 * 4096;
    unsigned short* X0h  = Wtk3 + (size_t)560 * 4096;        // 512*32*48
    unsigned short* H1   = X0h + (size_t)CIN_B * CIN_D * 48; // 512*32*224 each
    unsigned short* H2   = H1 + (size_t)CIN_B * CIN_D * 224;
    float* Xs = (float*)(H2 + (size_t)CIN_B * CIN_D * 224);  // 512*40*32 fp32
    // total ws ~29 MB

    prep_w<CIN_F0, 3><<<120, 256, 0, stream>>>(W0, Wtk1);
    prep_w2<<<1120, 256, 0, stream>>>(W1, Wtk2, W2, Wtk3);
    prep_x<<<(CIN_B * CIN_F0 * CIN_D) / 256, 256, 0, stream>>>(X, X0h, Xs);

    cin_layer<3, 48, true><<<CIN_B / 2, 896, 0, stream>>>(X0h, Xs, Wtk1, H1, out, 0);
    cin_layer<14, 224, true><<<CIN_B / 2, 896, 0, stream>>>(H1, Xs, Wtk2, H2, out, CIN_S);
    cin_layer<14, 224, false><<<CIN_B / 2, 896, 0, stream>>>(H2, Xs, Wtk3, nullptr, out, 2 * CIN_S);
}

// Round 8
// 362.080 us; speedup vs baseline: 1.8241x; 1.8241x over previous
//
#include <hip/hip_runtime.h>

#define CIN_B 512
#define CIN_F0 40
#define CIN_D 32
#define CIN_S 200

typedef short bf16x8 __attribute__((ext_vector_type(8)));
typedef float floatx16 __attribute__((ext_vector_type(16)));

__device__ __forceinline__ float bits2f(unsigned int u) {
    union { unsigned int i; float f; } c; c.i = u; return c.f;
}
__device__ __forceinline__ unsigned short f2b(float f) {
    union { float f; unsigned int i; } c; c.f = f;
    unsigned int i = c.i;
    return (unsigned short)((i + 0x7fffu + ((i >> 16) & 1u)) >> 16);  // RNE
}

// Wtk[kc][nn 0..255][kw 0..15] = bf16(W[(i*FI + kk*16+kw)*200 + nn]); kc=i*KCPI+kk.
// kk==HALVE rows stored as 0.5*W (read by BOTH j-halves; 0.5x+0.5x==x, exact in bf16).
template <int FI, int KCPI, int HALVE>
__global__ __launch_bounds__(256) void prep_w(const float* __restrict__ W,
                                              unsigned short* __restrict__ Wtk) {
    const int kc = blockIdx.x;
    const int nn = threadIdx.x;
    const int i = kc / KCPI;
    const int kk = kc - i * KCPI;
    const float sc = (kk == HALVE) ? 0.5f : 1.0f;
    unsigned short v[16];
#pragma unroll
    for (int kw = 0; kw < 16; ++kw) {
        int j = kk * 16 + kw;
        float f = 0.f;
        if (j < FI && nn < CIN_S) f = sc * W[(size_t)(i * FI + j) * CIN_S + nn];
        v[kw] = f2b(f);
    }
    uint4* dst = (uint4*)(Wtk + ((size_t)kc * 256 + nn) * 16);
    dst[0] = ((const uint4*)v)[0];
    dst[1] = ((const uint4*)v)[1];
}

// fused for the two big weight matrices; kc = i*13+kk, kk==6 halved
__global__ __launch_bounds__(256) void prep_w2(const float* __restrict__ Wa,
                                               unsigned short* __restrict__ Wta,
                                               const float* __restrict__ Wb,
                                               unsigned short* __restrict__ Wtb) {
    const int half = blockIdx.x >= 520;
    const int kc = half ? blockIdx.x - 520 : blockIdx.x;
    const float* W = half ? Wb : Wa;
    unsigned short* Wtk = half ? Wtb : Wta;
    const int nn = threadIdx.x;
    const int i = kc / 13;
    const int kk = kc - i * 13;
    const float sc = (kk == 6) ? 0.5f : 1.0f;
    unsigned short v[16];
#pragma unroll
    for (int kw = 0; kw < 16; ++kw) {
        int j = kk * 16 + kw;
        float f = 0.f;
        if (j < CIN_S && nn < CIN_S) f = sc * W[(size_t)(i * CIN_S + j) * CIN_S + nn];
        v[kw] = f2b(f);
    }
    uint4* dst = (uint4*)(Wtk + ((size_t)kc * 256 + nn) * 16);
    dst[0] = ((const uint4*)v)[0];
    dst[1] = ((const uint4*)v)[1];
}

// X0h[b][d][i(pad 48)] = bf16(x0[b][i][d])
__global__ __launch_bounds__(256) void prep_x(const float* __restrict__ X,
                                              unsigned short* __restrict__ X0h) {
    int e = blockIdx.x * 256 + threadIdx.x;   // 512*32*48
    int i = e % 48;
    int r = e / 48;
    int d = r & 31;
    int b = r >> 5;
    unsigned short v = 0;
    if (i < CIN_F0) v = f2b(X[(size_t)b * (CIN_F0 * CIN_D) + i * CIN_D + d]);
    X0h[e] = v;
}

// ---- layer 1 (K=1600, KCPI=3, unsplit, full acc) ----------------------------
// Grid 256 x 448thr = 7 waves; wave = 1 n-tile x 2 b. P-fold per b (sequential
// chains share one P). Writes H1 bf16 [b][32][224] and out[0,200) directly.
// mfma_f32_32x32x16_bf16: A[m=lane&31][k=(lane>>5)*8+e]; B[k][col=lane&31];
// C/D col=lane&31, row=(reg&3)+8*(reg>>2)+4*(lane>>5).
__global__ __launch_bounds__(448, 4)
void cin_layer1(const unsigned short* __restrict__ X0h,
                const float* __restrict__ X,
                const unsigned short* __restrict__ Wtk,
                unsigned short* __restrict__ H1,
                float* __restrict__ out) {
    const int b0 = blockIdx.x * 2;
    const int tile = threadIdx.x >> 6;       // 0..6
    const int lane = threadIdx.x & 63;
    const int l32 = lane & 31, hl = lane >> 5;

    bf16x8 Bf0[3], Bf1[3];
    {
        const unsigned short* h0 = X0h + ((size_t)b0 * CIN_D + l32) * 48 + hl * 8;
        const unsigned short* h1 = h0 + CIN_D * 48;
#pragma unroll
        for (int kk = 0; kk < 3; ++kk) {
            Bf0[kk] = *(const bf16x8*)(h0 + kk * 16);
            Bf1[kk] = *(const bf16x8*)(h1 + kk * 16);
        }
    }
    const unsigned short* Ab = Wtk + ((size_t)(tile * 32 + l32) * 16 + hl * 8);
    const float* xp = X + (size_t)b0 * (CIN_F0 * CIN_D) + l32;

    floatx16 acc0, acc1, z16;
#pragma unroll
    for (int r = 0; r < 16; ++r) { acc0[r] = 0.f; acc1[r] = 0.f; z16[r] = 0.f; }

#pragma unroll 1
    for (int i = 0; i < CIN_F0; ++i) {
        const float x0 = xp[i * CIN_D];
        const float x1 = xp[i * CIN_D + CIN_F0 * CIN_D];
        const unsigned short* Ai = Ab + (size_t)i * (3 * 4096);
        floatx16 P;
#pragma unroll
        for (int kk = 0; kk < 3; ++kk) {
            const bf16x8 Af = *(const bf16x8*)(Ai + kk * 4096);
            P = __builtin_amdgcn_mfma_f32_32x32x16_bf16(Af, Bf0[kk],
                                                        kk ? P : z16, 0, 0, 0);
        }
#pragma unroll
        for (int r = 0; r < 16; ++r) acc0[r] += x0 * P[r];
#pragma unroll
        for (int kk = 0; kk < 3; ++kk) {
            const bf16x8 Af = *(const bf16x8*)(Ai + kk * 4096);
            P = __builtin_amdgcn_mfma_f32_32x32x16_bf16(Af, Bf1[kk],
                                                        kk ? P : z16, 0, 0, 0);
        }
#pragma unroll
        for (int r = 0; r < 16; ++r) acc1[r] += x1 * P[r];
    }

#pragma unroll
    for (int bb = 0; bb < 2; ++bb) {
        const floatx16& a = bb ? acc1 : acc0;
        // H1 store: C[n][d] -> H1[b][d][n]
        unsigned short* dst = H1 + ((size_t)(b0 + bb) * CIN_D + l32) * 224 + tile * 32;
#pragma unroll
        for (int qd = 0; qd < 4; ++qd) {
            ushort4 pk;
            pk.x = f2b(a[4 * qd + 0]);
            pk.y = f2b(a[4 * qd + 1]);
            pk.z = f2b(a[4 * qd + 2]);
            pk.w = f2b(a[4 * qd + 3]);
            *(ushort4*)&dst[8 * qd + 4 * hl] = pk;
        }
        // out[b, n] = sum_d
#pragma unroll
        for (int r = 0; r < 16; ++r) {
            float v = a[r];
            v += __shfl_xor(v, 1);
            v += __shfl_xor(v, 2);
            v += __shfl_xor(v, 4);
            v += __shfl_xor(v, 8);
            v += __shfl_xor(v, 16);
            if (l32 == 0) {
                int n = tile * 32 + (r & 3) + 8 * (r >> 2) + 4 * hl;
                if (n < CIN_S)
                    out[(size_t)(b0 + bb) * (3 * CIN_S) + n] = v;
            }
        }
    }
}

// ---- big layers (K=8000, KCPI=13, j-half split over blockIdx.y) ------------
// Grid (256,2) x 448thr; wave = 1 n-tile x 2 b x j-half (7 kc, kk=6 shared &
// pre-halved). Partials: atomicAdd fp32 into Hacc[b][n][d] (WH) and out.
template <bool WH>
__global__ __launch_bounds__(448, 4)
void cin_layer_big(const unsigned short* __restrict__ Hin,  // [b][32][224] bf16
                   const float* __restrict__ X,             // [b][40][32] fp32
                   const unsigned short* __restrict__ Wtk,  // [kc][256][16]
                   float* __restrict__ Hacc,                // [b][208][32] fp32
                   float* __restrict__ out, int loff) {
    const int b0 = blockIdx.x * 2;
    const int jh = blockIdx.y;
    const int tile = threadIdx.x >> 6;       // 0..6
    const int lane = threadIdx.x & 63;
    const int l32 = lane & 31, hl = lane >> 5;
    const int kks = jh * 6;                  // kk 0..6 or 6..12

    bf16x8 Bf0[7], Bf1[7];
    {
        const unsigned short* h0 =
            Hin + ((size_t)b0 * CIN_D + l32) * 224 + kks * 16 + hl * 8;
        const unsigned short* h1 = h0 + CIN_D * 224;
#pragma unroll
        for (int kk = 0; kk < 7; ++kk) {
            Bf0[kk] = *(const bf16x8*)(h0 + kk * 16);
            Bf1[kk] = *(const bf16x8*)(h1 + kk * 16);
        }
    }
    const unsigned short* Ab =
        Wtk + ((size_t)(tile * 32 + l32) * 16 + hl * 8) + (size_t)kks * 4096;
    const float* xp = X + (size_t)b0 * (CIN_F0 * CIN_D) + l32;

    floatx16 acc0, acc1, z16;
#pragma unroll
    for (int r = 0; r < 16; ++r) { acc0[r] = 0.f; acc1[r] = 0.f; z16[r] = 0.f; }

#pragma unroll 1
    for (int i = 0; i < CIN_F0; ++i) {
        const float x0 = xp[i * CIN_D];
        const float x1 = xp[i * CIN_D + CIN_F0 * CIN_D];
        const unsigned short* Ai = Ab + (size_t)i * (13 * 4096);
        floatx16 P;
#pragma unroll
        for (int kk = 0; kk < 7; ++kk) {
            const bf16x8 Af = *(const bf16x8*)(Ai + kk * 4096);
            P = __builtin_amdgcn_mfma_f32_32x32x16_bf16(Af, Bf0[kk],
                                                        kk ? P : z16, 0, 0, 0);
        }
#pragma unroll
        for (int r = 0; r < 16; ++r) acc0[r] += x0 * P[r];
#pragma unroll
        for (int kk = 0; kk < 7; ++kk) {
            const bf16x8 Af = *(const bf16x8*)(Ai + kk * 4096);
            P = __builtin_amdgcn_mfma_f32_32x32x16_bf16(Af, Bf1[kk],
                                                        kk ? P : z16, 0, 0, 0);
        }
#pragma unroll
        for (int r = 0; r < 16; ++r) acc1[r] += x1 * P[r];
    }

#pragma unroll
    for (int bb = 0; bb < 2; ++bb) {
        const floatx16& a = bb ? acc1 : acc0;
        if constexpr (WH) {
            float* hb = Hacc + (size_t)(b0 + bb) * (208 * CIN_D) + l32;
#pragma unroll
            for (int r = 0; r < 16; ++r) {
                int n = tile * 32 + (r & 3) + 8 * (r >> 2) + 4 * hl;
                if (n < 208) atomicAdd(hb + (size_t)n * CIN_D, a[r]);
            }
        }
#pragma unroll
        for (int r = 0; r < 16; ++r) {
            float v = a[r];
            v += __shfl_xor(v, 1);
            v += __shfl_xor(v, 2);
            v += __shfl_xor(v, 4);
            v += __shfl_xor(v, 8);
            v += __shfl_xor(v, 16);
            if (l32 == 0) {
                int n = tile * 32 + (r & 3) + 8 * (r >> 2) + 4 * hl;
                if (n < CIN_S)
                    atomicAdd(&out[(size_t)(b0 + bb) * (3 * CIN_S) + loff + n], v);
            }
        }
    }
}

// Hacc[b][n 0..207][d] fp32 -> H[b][d][n] bf16 (LDS transpose), 1 block per b
__global__ __launch_bounds__(256) void cin_conv(const float* __restrict__ Hacc,
                                                unsigned short* __restrict__ H) {
    __shared__ float T[208][33];
    const int b = blockIdx.x;
    const float* src = Hacc + (size_t)b * (208 * CIN_D);
    for (int f = threadIdx.x; f < 208 * CIN_D; f += 256)
        T[f >> 5][f & 31] = src[f];
    __syncthreads();
    const int d = threadIdx.x >> 3, c = threadIdx.x & 7;   // 32 d x 8 chunks of 26
    unsigned short* dst = H + ((size_t)b * CIN_D + d) * 224 + c * 26;
#pragma unroll
    for (int q = 0; q < 26; q += 2) {
        ushort2 pk;
        pk.x = f2b(T[c * 26 + q][d]);
        pk.y = f2b(T[c * 26 + q + 1][d]);
        *(ushort2*)&dst[q] = pk;
    }
}

extern "C" void kernel_launch(void* const* d_in, const int* in_sizes, int n_in,
                              void* d_out, int out_size, void* d_ws, size_t ws_size,
                              hipStream_t stream) {
    const float* X  = (const float*)d_in[0];
    const float* W0 = (const float*)d_in[1];
    const float* W1 = (const float*)d_in[2];
    const float* W2 = (const float*)d_in[3];
    float* out = (float*)d_out;

    unsigned short* Wtk1 = (unsigned short*)d_ws;            // 120*4096
    unsigned short* Wtk2 = Wtk1 + (size_t)120 * 4096;        // 520*4096
    unsigned short* Wtk3 = Wtk2 + (size_t)520 * 4096;
    unsigned short* X0h  = Wtk3 + (size_t)520 * 4096;        // 512*32*48
    unsigned short* H1   = X0h + (size_t)CIN_B * CIN_D * 48; // 512*32*224
    unsigned short* H2   = H1 + (size_t)CIN_B * CIN_D * 224;
    float* Hacc = (float*)(H2 + (size_t)CIN_B * CIN_D * 224); // 512*208*32 fp32
    // total ws ~39.4 MB

    hipMemsetAsync(out, 0, (size_t)CIN_B * 3 * CIN_S * 4, stream);
    hipMemsetAsync(Hacc, 0, (size_t)CIN_B * 208 * CIN_D * 4, stream);

    prep_w<CIN_F0, 3, -1><<<120, 256, 0, stream>>>(W0, Wtk1);
    prep_w2<<<1040, 256, 0, stream>>>(W1, Wtk2, W2, Wtk3);
    prep_x<<<(CIN_B * CIN_D * 48) / 256, 256, 0, stream>>>(X, X0h);

    cin_layer1<<<CIN_B / 2, 448, 0, stream>>>(X0h, X, Wtk1, H1, out);
    cin_layer_big<true><<<dim3(CIN_B / 2, 2), 448, 0, stream>>>(H1, X, Wtk2, Hacc,
                                                                out, CIN_S);
    cin_conv<<<CIN_B, 256, 0, stream>>>(Hacc, H2);
    cin_layer_big<false><<<dim3(CIN_B / 2, 2), 448, 0, stream>>>(H2, X, Wtk3, nullptr,
                                                                 out, 2 * CIN_S);
}

// Round 9
// 321.828 us; speedup vs baseline: 2.0522x; 1.1251x over previous
//
#include <hip/hip_runtime.h>

#define CIN_B 512
#define CIN_F0 40
#define CIN_D 32
#define CIN_S 200

typedef short bf16x8 __attribute__((ext_vector_type(8)));
typedef float floatx16 __attribute__((ext_vector_type(16)));

__device__ __forceinline__ float bits2f(unsigned int u) {
    union { unsigned int i; float f; } c; c.i = u; return c.f;
}
__device__ __forceinline__ unsigned short f2b(float f) {
    union { float f; unsigned int i; } c; c.f = f;
    unsigned int i = c.i;
    return (unsigned short)((i + 0x7fffu + ((i >> 16) & 1u)) >> 16);  // RNE
}
__device__ __forceinline__ float b2f(unsigned short u) {
    return bits2f(((unsigned int)u) << 16);
}

// Wtk[kc][nn 0..255][kw 0..15] = bf16(W[(i*FI + kk*16+kw)*200 + nn]); kc=i*KCPI+kk.
template <int FI, int KCPI>
__global__ __launch_bounds__(256) void prep_w(const float* __restrict__ W,
                                              unsigned short* __restrict__ Wtk) {
    const int kc = blockIdx.x;
    const int nn = threadIdx.x;
    const int i = kc / KCPI;
    const int kk = kc - i * KCPI;
    unsigned short v[16];
#pragma unroll
    for (int kw = 0; kw < 16; ++kw) {
        int j = kk * 16 + kw;
        float f = 0.f;
        if (j < FI && nn < CIN_S) f = W[(size_t)(i * FI + j) * CIN_S + nn];
        v[kw] = f2b(f);
    }
    uint4* dst = (uint4*)(Wtk + ((size_t)kc * 256 + nn) * 16);
    dst[0] = ((const uint4*)v)[0];
    dst[1] = ((const uint4*)v)[1];
}

// fused for the two big weight matrices; kc = i*13+kk, kk==6 stored 0.5x (read
// by BOTH j-halves: 0.5x+0.5x == x, exact in bf16 scaling).
__global__ __launch_bounds__(256) void prep_w2(const float* __restrict__ Wa,
                                               unsigned short* __restrict__ Wta,
                                               const float* __restrict__ Wb,
                                               unsigned short* __restrict__ Wtb) {
    const int half = blockIdx.x >= 520;
    const int kc = half ? blockIdx.x - 520 : blockIdx.x;
    const float* W = half ? Wb : Wa;
    unsigned short* Wtk = half ? Wtb : Wta;
    const int nn = threadIdx.x;
    const int i = kc / 13;
    const int kk = kc - i * 13;
    const float sc = (kk == 6) ? 0.5f : 1.0f;
    unsigned short v[16];
#pragma unroll
    for (int kw = 0; kw < 16; ++kw) {
        int j = kk * 16 + kw;
        float f = 0.f;
        if (j < CIN_S && nn < CIN_S) f = sc * W[(size_t)(i * CIN_S + j) * CIN_S + nn];
        v[kw] = f2b(f);
    }
    uint4* dst = (uint4*)(Wtk + ((size_t)kc * 256 + nn) * 16);
    dst[0] = ((const uint4*)v)[0];
    dst[1] = ((const uint4*)v)[1];
}

// X0h[b][d][i(pad 48)] = bf16(x0[b][i][d])
__global__ __launch_bounds__(256) void prep_x(const float* __restrict__ X,
                                              unsigned short* __restrict__ X0h) {
    int e = blockIdx.x * 256 + threadIdx.x;   // 512*32*48
    int i = e % 48;
    int r = e / 48;
    int d = r & 31;
    int b = r >> 5;
    unsigned short v = 0;
    if (i < CIN_F0) v = f2b(X[(size_t)b * (CIN_F0 * CIN_D) + i * CIN_D + d]);
    X0h[e] = v;
}

// One layer (j-half per blockIdx.y for MODE 2/3). Block = 2 b x 7 waves (448).
// B-frags staged in LDS in fragment order: Bp[(bb*NKC+kk)*512 + lane*8] =
// h[bb][d=lane&31][j=(kks+kk)*16 + (lane>>5)*8 + e] -> conflict-free
// ds_read_b128, i-invariant, cheap to rematerialize (frees VGPRs for A hoist).
// MODE 1: Hsrc=X0h[b][d][48], writes H1 bf16 + out[0:200) direct (unsplit).
// MODE 2: Hsrc=H1[b][d][224], writes Hacc[jh][b][n][d] bf16 + outp partials.
// MODE 3: Hsrc=Hacc (both jh2 partials, combined in staging), writes outp only.
// mfma_f32_32x32x16_bf16: A[m=lane&31][k=(lane>>5)*8+e]; B[k][col=lane&31];
// C/D col=lane&31, row=(reg&3)+8*(reg>>2)+4*(lane>>5).
template <int NKC, int KCPI_TOT, int MODE>
__global__ __launch_bounds__(448, 4)
void cin_layer(const unsigned short* __restrict__ Hsrc,
               const float* __restrict__ X,
               const unsigned short* __restrict__ Wtk,
               unsigned short* __restrict__ Hout,
               float* __restrict__ outp) {
    constexpr int JROW = (MODE == 1) ? 48 : 224;
    __shared__ __align__(16) unsigned short Bp[2 * NKC * 512];
    const int tid = threadIdx.x;
    const int b0 = blockIdx.x * 2;
    const int jh = (MODE == 1) ? 0 : blockIdx.y;
    const int kks = jh * 6;

    // ---- stage B-frags into LDS ----
    if constexpr (MODE != 3) {
        const int j0 = (MODE == 1) ? 0 : jh * 96;
        uint4* Bpu = (uint4*)Bp;
        for (int g = tid; g < 2 * 64 * NKC; g += 448) {
            int bb = g / (64 * NKC), r = g - bb * (64 * NKC);
            int d = r / (2 * NKC), c = r - d * (2 * NKC);
            uint4 v = ((const uint4*)Hsrc)[(((size_t)(b0 + bb) * CIN_D + d) * JROW + j0) / 8 + c];
            Bpu[(bb * NKC + (c >> 1)) * 64 + (c & 1) * 32 + d] = v;
        }
    } else {
        // combine the two jh2 partials of H2 while staging
        uint4* Bpu = (uint4*)Bp;
        for (int g = tid; g < 2 * NKC * 64; g += 448) {
            int bb = g / (NKC * 64), r = g - bb * (NKC * 64);
            int kk = r >> 6, r2 = r & 63, hl = r2 >> 5, d = r2 & 31;
            const unsigned short* p0 = Hsrc + ((size_t)(b0 + bb) * 208 + 0) * CIN_D + d;
            const unsigned short* p1 = p0 + (size_t)512 * 208 * CIN_D;
            unsigned short v[8];
#pragma unroll
            for (int q = 0; q < 8; ++q) {
                int n = (kks + kk) * 16 + hl * 8 + q;
                v[q] = f2b(b2f(p0[(size_t)n * CIN_D]) + b2f(p1[(size_t)n * CIN_D]));
            }
            Bpu[(bb * NKC + kk) * 64 + hl * 32 + d] = *(const uint4*)v;
        }
    }
    __syncthreads();

    const int tile = tid >> 6;              // 0..6
    const int lane = tid & 63;
    const int l32 = lane & 31, hl = lane >> 5;

    const unsigned short* Abase =
        Wtk + ((size_t)(tile * 32 + l32) * 16 + hl * 8) + (size_t)kks * 4096;
    const float* xp = X + (size_t)b0 * (CIN_F0 * CIN_D) + l32;

    floatx16 acc0, acc1, z16;
#pragma unroll
    for (int r = 0; r < 16; ++r) { acc0[r] = 0.f; acc1[r] = 0.f; z16[r] = 0.f; }

#pragma unroll 1
    for (int i = 0; i < CIN_F0; ++i) {
        const float x0 = xp[i * CIN_D];
        const float x1 = xp[i * CIN_D + CIN_F0 * CIN_D];
        const unsigned short* Ai = Abase + (size_t)i * (KCPI_TOT * 4096);
        floatx16 P0, P1;
#pragma unroll
        for (int kk = 0; kk < NKC; ++kk) {
            const bf16x8 Af = *(const bf16x8*)(Ai + kk * 4096);
            const bf16x8 Bf0 = *(const bf16x8*)&Bp[(0 * NKC + kk) * 512 + lane * 8];
            const bf16x8 Bf1 = *(const bf16x8*)&Bp[(1 * NKC + kk) * 512 + lane * 8];
            P0 = __builtin_amdgcn_mfma_f32_32x32x16_bf16(Af, Bf0, kk ? P0 : z16, 0, 0, 0);
            P1 = __builtin_amdgcn_mfma_f32_32x32x16_bf16(Af, Bf1, kk ? P1 : z16, 0, 0, 0);
        }
#pragma unroll
        for (int r = 0; r < 16; ++r) {
            acc0[r] += x0 * P0[r];
            acc1[r] += x1 * P1[r];
        }
    }

    // ---- epilogue ----
#pragma unroll
    for (int bb = 0; bb < 2; ++bb) {
        const floatx16& a = bb ? acc1 : acc0;

        if constexpr (MODE == 1) {   // H1[b][d][n] bf16, n-tile of 32
            unsigned short* dst =
                Hout + ((size_t)(b0 + bb) * CIN_D + l32) * 224 + tile * 32;
#pragma unroll
            for (int qd = 0; qd < 4; ++qd) {
                ushort4 pk;
                pk.x = f2b(a[4 * qd + 0]);
                pk.y = f2b(a[4 * qd + 1]);
                pk.z = f2b(a[4 * qd + 2]);
                pk.w = f2b(a[4 * qd + 3]);
                *(ushort4*)&dst[8 * qd + 4 * hl] = pk;
            }
        }
        if constexpr (MODE == 2) {   // Hacc[jh][b][n][d] bf16, coalesced d
            unsigned short* hb =
                Hout + (((size_t)jh * CIN_B + b0 + bb) * 208) * CIN_D + l32;
#pragma unroll
            for (int r = 0; r < 16; ++r) {
                int n = tile * 32 + (r & 3) + 8 * (r >> 2) + 4 * hl;
                if (n < 208) hb[(size_t)n * CIN_D] = f2b(a[r]);
            }
        }

        // d-sum (over col = l32 within each hl half)
#pragma unroll
        for (int r = 0; r < 16; ++r) {
            float v = a[r];
            v += __shfl_xor(v, 1);
            v += __shfl_xor(v, 2);
            v += __shfl_xor(v, 4);
            v += __shfl_xor(v, 8);
            v += __shfl_xor(v, 16);
            if (l32 == 0) {
                int n = tile * 32 + (r & 3) + 8 * (r >> 2) + 4 * hl;
                if (n < CIN_S) {
                    if constexpr (MODE == 1)
                        outp[(size_t)(b0 + bb) * (3 * CIN_S) + n] = v;   // direct out
                    else
                        outp[((size_t)jh * CIN_B + b0 + bb) * CIN_S + n] = v;
                }
            }
        }
    }
}

// out[b, 200+t] from jh-partial sums (t in [0,400))
__global__ __launch_bounds__(256) void cin_outc(const float* __restrict__ p2,
                                                const float* __restrict__ p3,
                                                float* __restrict__ out) {
    int e = blockIdx.x * 256 + threadIdx.x;   // 512*400 exact
    int b = e / 400, t = e - b * 400;
    int half = t / 200, n = t - half * 200;
    const float* p = half ? p3 : p2;
    out[(size_t)b * 600 + 200 + half * 200 + n] =
        p[(size_t)b * CIN_S + n] + p[(size_t)(CIN_B + b) * CIN_S + n];
}

extern "C" void kernel_launch(void* const* d_in, const int* in_sizes, int n_in,
                              void* d_out, int out_size, void* d_ws, size_t ws_size,
                              hipStream_t stream) {
    const float* X  = (const float*)d_in[0];
    const float* W0 = (const float*)d_in[1];
    const float* W1 = (const float*)d_in[2];
    const float* W2 = (const float*)d_in[3];
    float* out = (float*)d_out;

    unsigned short* Wtk1 = (unsigned short*)d_ws;             // 120*4096
    unsigned short* Wtk2 = Wtk1 + (size_t)120 * 4096;         // 520*4096 each
    unsigned short* Wtk3 = Wtk2 + (size_t)520 * 4096;
    unsigned short* X0h  = Wtk3 + (size_t)520 * 4096;         // 512*32*48
    unsigned short* H1   = X0h + (size_t)CIN_B * CIN_D * 48;  // 512*32*224
    unsigned short* Hacc = H1 + (size_t)CIN_B * CIN_D * 224;  // 2*512*208*32 bf16
    float* outp2 = (float*)(Hacc + (size_t)2 * CIN_B * 208 * CIN_D);  // 2*512*200
    float* outp3 = outp2 + (size_t)2 * CIN_B * CIN_S;
    // total ws ~47.3 MB

    prep_w<CIN_F0, 3><<<120, 256, 0, stream>>>(W0, Wtk1);
    prep_w2<<<1040, 256, 0, stream>>>(W1, Wtk2, W2, Wtk3);
    prep_x<<<(CIN_B * CIN_D * 48) / 256, 256, 0, stream>>>(X, X0h);

    cin_layer<3, 3, 1><<<dim3(CIN_B / 2, 1), 448, 0, stream>>>(X0h, X, Wtk1, H1, out);
    cin_layer<7, 13, 2><<<dim3(CIN_B / 2, 2), 448, 0, stream>>>(H1, X, Wtk2, Hacc, outp2);
    cin_layer<7, 13, 3><<<dim3(CIN_B / 2, 2), 448, 0, stream>>>(Hacc, X, Wtk3, nullptr, outp3);

    cin_outc<<<(CIN_B * 400) / 256, 256, 0, stream>>>(outp2, outp3, out);
}

// Round 10
// 285.371 us; speedup vs baseline: 2.3144x; 1.1277x over previous
//
#include <hip/hip_runtime.h>

#define CIN_B 512
#define CIN_F0 40
#define CIN_D 32
#define CIN_S 200

typedef _Float16 f16x8 __attribute__((ext_vector_type(8)));
typedef float floatx16 __attribute__((ext_vector_type(16)));

__device__ __forceinline__ unsigned short f2h(float f) {
    _Float16 h = (_Float16)f;           // RNE
    return *(unsigned short*)&h;
}
__device__ __forceinline__ float h2f(unsigned short u) {
    return (float)(*(_Float16*)&u);
}

// Wtk[kc][nn 0..255][kw 0..15] = f16(W[(i*FI + kk*16+kw)*200 + nn]); kc=i*KCPI+kk.
template <int FI, int KCPI>
__global__ __launch_bounds__(256) void prep_w(const float* __restrict__ W,
                                              unsigned short* __restrict__ Wtk) {
    const int kc = blockIdx.x;
    const int nn = threadIdx.x;
    const int i = kc / KCPI;
    const int kk = kc - i * KCPI;
    unsigned short v[16];
#pragma unroll
    for (int kw = 0; kw < 16; ++kw) {
        int j = kk * 16 + kw;
        float f = 0.f;
        if (j < FI && nn < CIN_S) f = W[(size_t)(i * FI + j) * CIN_S + nn];
        v[kw] = f2h(f);
    }
    uint4* dst = (uint4*)(Wtk + ((size_t)kc * 256 + nn) * 16);
    dst[0] = ((const uint4*)v)[0];
    dst[1] = ((const uint4*)v)[1];
}

// fused for the two big weight matrices; kc = i*13+kk, kk==6 stored 0.5x (read
// by BOTH j-halves: 0.5x + 0.5x == x; 0.5 scaling exact in fp16).
__global__ __launch_bounds__(256) void prep_w2(const float* __restrict__ Wa,
                                               unsigned short* __restrict__ Wta,
                                               const float* __restrict__ Wb,
                                               unsigned short* __restrict__ Wtb) {
    const int half = blockIdx.x >= 520;
    const int kc = half ? blockIdx.x - 520 : blockIdx.x;
    const float* W = half ? Wb : Wa;
    unsigned short* Wtk = half ? Wtb : Wta;
    const int nn = threadIdx.x;
    const int i = kc / 13;
    const int kk = kc - i * 13;
    const float sc = (kk == 6) ? 0.5f : 1.0f;
    unsigned short v[16];
#pragma unroll
    for (int kw = 0; kw < 16; ++kw) {
        int j = kk * 16 + kw;
        float f = 0.f;
        if (j < CIN_S && nn < CIN_S) f = sc * W[(size_t)(i * CIN_S + j) * CIN_S + nn];
        v[kw] = f2h(f);
    }
    uint4* dst = (uint4*)(Wtk + ((size_t)kc * 256 + nn) * 16);
    dst[0] = ((const uint4*)v)[0];
    dst[1] = ((const uint4*)v)[1];
}

// X0hd[b][d][i(pad 48)] = f16(x0[b][i][d])  (layer1 B-source, d-major)
// Xh[b][i][d] = f16(x0[b][i][d])            (scale source, all layers)
__global__ __launch_bounds__(256) void prep_x(const float* __restrict__ X,
                                              unsigned short* __restrict__ X0hd,
                                              unsigned short* __restrict__ Xh) {
    int e = blockIdx.x * 256 + threadIdx.x;   // 512*40*32
    int d = e & 31;
    int rest = e >> 5;
    int i = rest % CIN_F0;
    int b = rest / CIN_F0;
    unsigned short v = f2h(X[e]);
    Xh[e] = v;
    X0hd[((size_t)b * CIN_D + d) * 48 + i] = v;
    if (e < CIN_B * CIN_D * 8) {     // zero pads i=40..47
        int q = e & 7, dd = (e >> 3) & 31, bb = e >> 8;
        X0hd[((size_t)bb * CIN_D + dd) * 48 + 40 + q] = 0;
    }
}

// One layer (j-half per blockIdx.y for MODE 2/3). Block = 2 b x 7 waves (448).
// x0 folded into B via v_pk_mul_f16 (4 ops/frag) -> acc is the MFMA C operand
// directly: NO P accumulator, only 32 AGPRs/wave -> ~90 arch VGPRs free for
// A-stream pipelining at 2 blocks/CU.
// B-frags staged in LDS in fragment order (conflict-free ds_read_b128,
// i-invariant). MODE 1: Hsrc=X0hd, unsplit, writes H1 + out direct.
// MODE 2: writes Hacc[jh][b][n][d] f16 partials + outp. MODE 3: combines the
// two jh partials of H2 during staging, writes outp only.
// mfma_f32_32x32x16_f16: A[m=lane&31][k=(lane>>5)*8+e]; B[k][col=lane&31];
// C/D col=lane&31, row=(reg&3)+8*(reg>>2)+4*(lane>>5).
template <int NKC, int KCPI_TOT, int MODE>
__global__ __launch_bounds__(448, 4)
void cin_layer(const unsigned short* __restrict__ Hsrc,
               const unsigned short* __restrict__ Xh,
               const unsigned short* __restrict__ Wtk,
               unsigned short* __restrict__ Hout,
               float* __restrict__ outp) {
    constexpr int JROW = (MODE == 1) ? 48 : 224;
    __shared__ __align__(16) unsigned short Bp[2 * NKC * 512];
    const int tid = threadIdx.x;
    const int b0 = blockIdx.x * 2;
    const int jh = (MODE == 1) ? 0 : blockIdx.y;
    const int kks = jh * 6;

    // ---- stage B-frags into LDS ----
    if constexpr (MODE != 3) {
        const int j0 = (MODE == 1) ? 0 : jh * 96;
        uint4* Bpu = (uint4*)Bp;
        for (int g = tid; g < 2 * 64 * NKC; g += 448) {
            int bb = g / (64 * NKC), r = g - bb * (64 * NKC);
            int d = r / (2 * NKC), c = r - d * (2 * NKC);
            uint4 v = ((const uint4*)Hsrc)[(((size_t)(b0 + bb) * CIN_D + d) * JROW + j0) / 8 + c];
            Bpu[(bb * NKC + (c >> 1)) * 64 + (c & 1) * 32 + d] = v;
        }
    } else {
        uint4* Bpu = (uint4*)Bp;
        for (int g = tid; g < 2 * NKC * 64; g += 448) {
            int bb = g / (NKC * 64), r = g - bb * (NKC * 64);
            int kk = r >> 6, r2 = r & 63, hl = r2 >> 5, d = r2 & 31;
            const unsigned short* p0 = Hsrc + ((size_t)(b0 + bb) * 208) * CIN_D + d;
            const unsigned short* p1 = p0 + (size_t)CIN_B * 208 * CIN_D;
            unsigned short v[8];
#pragma unroll
            for (int q = 0; q < 8; ++q) {
                int n = (kks + kk) * 16 + hl * 8 + q;
                v[q] = f2h(h2f(p0[(size_t)n * CIN_D]) + h2f(p1[(size_t)n * CIN_D]));
            }
            Bpu[(bb * NKC + kk) * 64 + hl * 32 + d] = *(const uint4*)v;
        }
    }
    __syncthreads();

    const int tile = tid >> 6;              // 0..6
    const int lane = tid & 63;
    const int l32 = lane & 31, hl = lane >> 5;

    const unsigned short* Abase =
        Wtk + ((size_t)(tile * 32 + l32) * 16 + hl * 8) + (size_t)kks * 4096;
    const _Float16* xp = (const _Float16*)Xh + (size_t)b0 * (CIN_F0 * CIN_D) + l32;

    floatx16 acc0, acc1;
#pragma unroll
    for (int r = 0; r < 16; ++r) { acc0[r] = 0.f; acc1[r] = 0.f; }

#pragma unroll 1
    for (int i = 0; i < CIN_F0; ++i) {
        const _Float16 x0 = xp[i * CIN_D];
        const _Float16 x1 = xp[i * CIN_D + CIN_F0 * CIN_D];
        f16x8 xs0, xs1;
#pragma unroll
        for (int r = 0; r < 8; ++r) { xs0[r] = x0; xs1[r] = x1; }
        const unsigned short* Ai = Abase + (size_t)i * (KCPI_TOT * 4096);
#pragma unroll
        for (int kk = 0; kk < NKC; ++kk) {
            const f16x8 Af = *(const f16x8*)(Ai + kk * 4096);
            const f16x8 B0 = *(const f16x8*)&Bp[(0 * NKC + kk) * 512 + lane * 8] * xs0;
            const f16x8 B1 = *(const f16x8*)&Bp[(1 * NKC + kk) * 512 + lane * 8] * xs1;
            acc0 = __builtin_amdgcn_mfma_f32_32x32x16_f16(Af, B0, acc0, 0, 0, 0);
            acc1 = __builtin_amdgcn_mfma_f32_32x32x16_f16(Af, B1, acc1, 0, 0, 0);
        }
    }

    // ---- epilogue ----
#pragma unroll
    for (int bb = 0; bb < 2; ++bb) {
        const floatx16& a = bb ? acc1 : acc0;

        if constexpr (MODE == 1) {   // H1[b][d][n] f16, n-tile of 32
            unsigned short* dst =
                Hout + ((size_t)(b0 + bb) * CIN_D + l32) * 224 + tile * 32;
#pragma unroll
            for (int qd = 0; qd < 4; ++qd) {
                ushort4 pk;
                pk.x = f2h(a[4 * qd + 0]);
                pk.y = f2h(a[4 * qd + 1]);
                pk.z = f2h(a[4 * qd + 2]);
                pk.w = f2h(a[4 * qd + 3]);
                *(ushort4*)&dst[8 * qd + 4 * hl] = pk;
            }
        }
        if constexpr (MODE == 2) {   // Hacc[jh][b][n][d] f16, coalesced d
            unsigned short* hb =
                Hout + (((size_t)jh * CIN_B + b0 + bb) * 208) * CIN_D + l32;
#pragma unroll
            for (int r = 0; r < 16; ++r) {
                int n = tile * 32 + (r & 3) + 8 * (r >> 2) + 4 * hl;
                if (n < 208) hb[(size_t)n * CIN_D] = f2h(a[r]);
            }
        }

        // d-sum over col = l32 (fp32)
#pragma unroll
        for (int r = 0; r < 16; ++r) {
            float v = a[r];
            v += __shfl_xor(v, 1);
            v += __shfl_xor(v, 2);
            v += __shfl_xor(v, 4);
            v += __shfl_xor(v, 8);
            v += __shfl_xor(v, 16);
            if (l32 == 0) {
                int n = tile * 32 + (r & 3) + 8 * (r >> 2) + 4 * hl;
                if (n < CIN_S) {
                    if constexpr (MODE == 1)
                        outp[(size_t)(b0 + bb) * (3 * CIN_S) + n] = v;   // direct out
                    else
                        outp[((size_t)jh * CIN_B + b0 + bb) * CIN_S + n] = v;
                }
            }
        }
    }
}

// out[b, 200+t] from jh-partial sums (t in [0,400))
__global__ __launch_bounds__(256) void cin_outc(const float* __restrict__ p2,
                                                const float* __restrict__ p3,
                                                float* __restrict__ out) {
    int e = blockIdx.x * 256 + threadIdx.x;   // 512*400 exact
    int b = e / 400, t = e - b * 400;
    int half = t / 200, n = t - half * 200;
    const float* p = half ? p3 : p2;
    out[(size_t)b * 600 + 200 + half * 200 + n] =
        p[(size_t)b * CIN_S + n] + p[(size_t)(CIN_B + b) * CIN_S + n];
}

extern "C" void kernel_launch(void* const* d_in, const int* in_sizes, int n_in,
                              void* d_out, int out_size, void* d_ws, size_t ws_size,
                              hipStream_t stream) {
    const float* X  = (const float*)d_in[0];
    const float* W0 = (const float*)d_in[1];
    const float* W1 = (const float*)d_in[2];
    const float* W2 = (const float*)d_in[3];
    float* out = (float*)d_out;

    unsigned short* Wtk1 = (unsigned short*)d_ws;             // 120*4096
    unsigned short* Wtk2 = Wtk1 + (size_t)120 * 4096;         // 520*4096 each
    unsigned short* Wtk3 = Wtk2 + (size_t)520 * 4096;
    unsigned short* X0hd = Wtk3 + (size_t)520 * 4096;         // 512*32*48
    unsigned short* Xh   = X0hd + (size_t)CIN_B * CIN_D * 48; // 512*40*32
    unsigned short* H1   = Xh + (size_t)CIN_B * CIN_F0 * CIN_D; // 512*32*224
    unsigned short* Hacc = H1 + (size_t)CIN_B * CIN_D * 224;  // 2*512*208*32 f16
    float* outp2 = (float*)(Hacc + (size_t)2 * CIN_B * 208 * CIN_D);  // 2*512*200
    float* outp3 = outp2 + (size_t)2 * CIN_B * CIN_S;
    // total ws ~49 MB

    prep_w<CIN_F0, 3><<<120, 256, 0, stream>>>(W0, Wtk1);
    prep_w2<<<1040, 256, 0, stream>>>(W1, Wtk2, W2, Wtk3);
    prep_x<<<(CIN_B * CIN_F0 * CIN_D) / 256, 256, 0, stream>>>(X, X0hd, Xh);

    cin_layer<3, 3, 1><<<dim3(CIN_B / 2, 1), 448, 0, stream>>>(X0hd, Xh, Wtk1, H1, out);
    cin_layer<7, 13, 2><<<dim3(CIN_B / 2, 2), 448, 0, stream>>>(H1, Xh, Wtk2, Hacc, outp2);
    cin_layer<7, 13, 3><<<dim3(CIN_B / 2, 2), 448, 0, stream>>>(Hacc, Xh, Wtk3, nullptr, outp3);

    cin_outc<<<(CIN_B * 400) / 256, 256, 0, stream>>>(outp2, outp3, out);
}